// Round 5
// baseline (15.589 us; speedup 1.0000x reference)
//
#include <hip/hip_runtime.h>
#include <math.h>

#define B_ 64
#define N_ 32
#define H_ 200
#define W_ 200
#define NSEG (N_ - 1)
#define TS 32                 // tile is 32x32 pixels, 4 px/thread (2x2)
#define NT 7                  // ceil(200/32)
// tile half-diagonal: sqrt(15.5^2+15.5^2)/200 = 0.1096 + margin
#define TILE_RAD 0.111f

__global__ __launch_bounds__(256) void stroke_kernel(
    const float* __restrict__ param,      // (B, N, 3)
    const float* __restrict__ x_start,
    const float* __restrict__ y_start,
    const float* __restrict__ theta,
    const float* __restrict__ weights,    // (2,2)
    const float* __restrict__ biases,     // (2,)
    const float* __restrict__ thick_mult,
    const float* __restrict__ thick_bias,
    const float* __restrict__ dark_exp_p,
    const float* __restrict__ dark_nlw_p,
    const float* __restrict__ x_m_p,
    const float* __restrict__ y_m_p,
    const float* __restrict__ x_b_p,
    const float* __restrict__ y_b_p,
    float* __restrict__ out)              // (B, H, W)
{
    // Benign-race LDS: every wave writes identical values, reads only after
    // its own writes (in-wave lgkmcnt order) -> NO __syncthreads in kernel.
    __shared__ float4 s_A[NSEG];   // (vy, vx, wvy, wvx)
    __shared__ float4 s_B[NSEG];   // (inv_d2, c0, c1, ddot_x = wvx*inv_d2/W)

    const int b    = blockIdx.z;
    const int tid  = threadIdx.x;
    const int lane = tid & 63;

    const float dexp = dark_exp_p[0], dnlw = dark_nlw_p[0];

    // ---- per-wave redundant setup (lanes 0..31) ----
    float sy = 0.0f, sx = 0.0f, tk = 0.0f;
    const float tm = thick_mult[0], tb = thick_bias[0];
    if (lane < N_) {
        const float thv = theta[0];
        const float c   = __cosf(thv), s = __sinf(thv);   // native v_cos/v_sin
        const float xs  = x_start[0], ys = y_start[0];
        const float W00 = weights[0], W01 = weights[1];
        const float W10 = weights[2], W11 = weights[3];
        const float bb0 = biases[0],  bb1 = biases[1];
        const float xm  = x_m_p[0], ym = y_m_p[0];
        const float xb  = x_b_p[0], yb = y_b_p[0];
        float p0 = param[(b * N_ + lane) * 3 + 0];
        float p1 = param[(b * N_ + lane) * 3 + 1];
        float p2 = param[(b * N_ + lane) * 3 + 2];
        float x0 = p0, y0 = -p1;
        float x_rot =  x0 * c + y0 * s;
        float y_rot = -x0 * s + y0 * c;
        float yy = y_rot * ym + yb + ys;
        float xx = x_rot * xm + xb + xs;
        sy = yy * W00 + xx * W01 + bb0;
        sx = yy * W10 + xx * W11 + bb1;
        tk = (p2 * 2.0f + 0.5f) * (1.0f / 64.0f);
    }
    float sy1 = __shfl_down(sy, 1);
    float sx1 = __shfl_down(sx, 1);
    float tk1 = __shfl_down(tk, 1);

    bool keep = false;
    float4 A4 = make_float4(0,0,0,0), B4 = make_float4(0,0,0,0);
    if (lane < NSEG) {
        float wvy = sy1 - sy, wvx = sx1 - sx;
        float d2 = wvy * wvy + wvx * wvx;
        float inv_d2 = 1.0f / (d2 + 1e-5f);
        float c0 = tk * tm + tb;            // th(frac) = c0 + frac*c1
        float c1 = (tk1 - tk) * tm;
        A4 = make_float4(sy, sx, wvy, wvx);
        B4 = make_float4(inv_d2, c0, c1, wvx * inv_d2 * (1.0f / W_));
        const float cy = ((float)(blockIdx.y * TS) + 15.5f) * (1.0f / H_);
        const float cx = ((float)(blockIdx.x * TS) + 15.5f) * (1.0f / W_);
        float dyc = cy - sy, dxc = cx - sx;
        float dot = (dyc * wvy + dxc * wvx) * inv_d2;
        float fr  = __builtin_amdgcn_fmed3f(dot, 0.0f, 1.0f);
        float ey  = dyc - fr * wvy;
        float ex  = dxc - fr * wvx;
        float e2c = ey * ey + ex * ex;
        float thmax = fmaxf(fmaxf(c0, c0 + c1), 1e-8f);
        float reach = thmax + TILE_RAD;     // beyond -> dark==0 in whole tile
        keep = e2c < reach * reach;
    }
    unsigned long long mask = __ballot(keep);
    const int cnt = (int)__popcll(mask);
    if (keep) {
        int pos = (int)__popcll(mask & ((1ull << lane) - 1ull));
        s_A[pos] = A4; s_B[pos] = B4;
    }
    // wave's own writes must land before its reads (no cross-wave dependency)
    asm volatile("s_waitcnt lgkmcnt(0)" ::: "memory");

    // ---- 2x2 pixels per thread ----
    const int ii = tid >> 4, jj = tid & 15;
    const int r0 = blockIdx.y * TS + ii;          // rows r0 and r0+16
    const int c0 = blockIdx.x * TS + (jj << 1);   // cols c0 and c0+1 (even)
    const float py0 = (float)r0 * (1.0f / H_);
    const float py1 = py0 + 16.0f / H_;
    const float px0 = (float)c0 * (1.0f / W_);
    const float px1 = px0 + 1.0f / W_;

    const bool hoist = (dexp > 0.0f) && (dnlw >= 0.0f) && (dnlw <= 1.0f);

    float r00, r01, r10, r11;
    if (hoist) {
        // maximize dark = 1 - sqrt(e2)/th  <=>  minimize q = e2*rcp(th)^2;
        // sqrt once per pixel; final clamp01 subsumes per-seg clamp + culled 0s.
        float q00 = INFINITY, q01 = INFINITY, q10 = INFINITY, q11 = INFINITY;
        if (cnt > 0) {
            float4 A = s_A[0], Bc = s_B[0];
            for (int n = 0; n < cnt; ++n) {
                int np = (n + 1 < cnt) ? n + 1 : n;   // prefetch next
                float4 An = s_A[np], Bn = s_B[np];
                float dy0 = py0 - A.x, dy1 = py1 - A.x;
                float dx0 = px0 - A.y, dx1 = px1 - A.y;
                float dot00 = fmaf(dy0, A.z, dx0 * A.w) * Bc.x;
                float ddy   = (A.z * Bc.x) * (16.0f / H_);
                float dot01 = dot00 + Bc.w;
                float dot10 = dot00 + ddy;
                float dot11 = dot10 + Bc.w;
                #define PX(dotv, dyv, dxv, qm) { \
                    float fr = __builtin_amdgcn_fmed3f(dotv, 0.0f, 1.0f); \
                    float ey = fmaf(-fr, A.z, dyv); \
                    float ex = fmaf(-fr, A.w, dxv); \
                    float e2 = fmaf(ey, ey, ex * ex); \
                    float th = fmaxf(fmaf(fr, Bc.z, Bc.y), 1e-8f); \
                    float it = __builtin_amdgcn_rcpf(th); \
                    qm = fminf(qm, (e2 * it) * it); }
                PX(dot00, dy0, dx0, q00)
                PX(dot01, dy0, dx1, q01)
                PX(dot10, dy1, dx0, q10)
                PX(dot11, dy1, dx1, q11)
                #undef PX
                A = An; Bc = Bn;
            }
        }
        const bool lin = (dexp == 1.0f);     // uniform: skip pow entirely
        #define EPI(qm, rr) { \
            float md = fminf(fmaxf(1.0f - __builtin_amdgcn_sqrtf(qm), 0.0f), 1.0f); \
            float d  = lin ? (md + 1e-4f) : __expf(dexp * __logf(md + 1e-4f)); \
            float nl = __builtin_amdgcn_rcpf(1.0f + __expf(8.0f - d * 16.0f)); \
            rr = dnlw * nl + (1.0f - dnlw) * d; }
        EPI(q00, r00) EPI(q01, r01) EPI(q10, r10) EPI(q11, r11)
        #undef EPI
    } else {
        // generic fallback: per-segment transform; culled segs contribute T(0)
        float b00 = -INFINITY, b01 = -INFINITY, b10 = -INFINITY, b11 = -INFINITY;
        if (cnt < NSEG) {
            float d0  = __expf(dexp * __logf(1e-4f));
            float nl0 = __builtin_amdgcn_rcpf(1.0f + __expf(8.0f - d0 * 16.0f));
            float t0  = dnlw * nl0 + (1.0f - dnlw) * d0;
            b00 = b01 = b10 = b11 = t0;
        }
        for (int n = 0; n < cnt; ++n) {
            float4 A = s_A[n], Bc = s_B[n];
            float dy0 = py0 - A.x, dy1 = py1 - A.x;
            float dx0 = px0 - A.y, dx1 = px1 - A.y;
            float dot00 = fmaf(dy0, A.z, dx0 * A.w) * Bc.x;
            float ddy   = (A.z * Bc.x) * (16.0f / H_);
            float dot01 = dot00 + Bc.w;
            float dot10 = dot00 + ddy;
            float dot11 = dot10 + Bc.w;
            #define PXF(dotv, dyv, dxv, bb) { \
                float fr = __builtin_amdgcn_fmed3f(dotv, 0.0f, 1.0f); \
                float ey = fmaf(-fr, A.z, dyv); \
                float ex = fmaf(-fr, A.w, dxv); \
                float dist = __builtin_amdgcn_sqrtf(fmaf(ey, ey, ex * ex)); \
                float th = fmaxf(fmaf(fr, Bc.z, Bc.y), 1e-8f); \
                float dark = fminf(fmaxf(fmaf(-dist, __builtin_amdgcn_rcpf(th), 1.0f), 0.0f), 1.0f); \
                float d  = __expf(dexp * __logf(dark + 1e-4f)); \
                float nl = __builtin_amdgcn_rcpf(1.0f + __expf(8.0f - d * 16.0f)); \
                bb = fmaxf(bb, dnlw * nl + (1.0f - dnlw) * d); }
            PXF(dot00, dy0, dx0, b00)
            PXF(dot01, dy0, dx1, b01)
            PXF(dot10, dy1, dx0, b10)
            PXF(dot11, dy1, dx1, b11)
            #undef PXF
        }
        r00 = b00; r01 = b01; r10 = b10; r11 = b11;
    }

    if (c0 < W_) {   // c0 even, W even -> pair never straddles the edge
        if (r0 < H_)
            *reinterpret_cast<float2*>(&out[(b * H_ + r0) * W_ + c0]) = make_float2(r00, r01);
        int r1 = r0 + 16;
        if (r1 < H_)
            *reinterpret_cast<float2*>(&out[(b * H_ + r1) * W_ + c0]) = make_float2(r10, r11);
    }
}

extern "C" void kernel_launch(void* const* d_in, const int* in_sizes, int n_in,
                              void* d_out, int out_size, void* d_ws, size_t ws_size,
                              hipStream_t stream) {
    const float* param      = (const float*)d_in[0];
    const float* x_start    = (const float*)d_in[1];
    const float* y_start    = (const float*)d_in[2];
    const float* theta      = (const float*)d_in[3];
    const float* weights    = (const float*)d_in[4];
    const float* biases     = (const float*)d_in[5];
    const float* thick_mult = (const float*)d_in[6];
    const float* thick_bias = (const float*)d_in[7];
    const float* dark_exp   = (const float*)d_in[8];
    const float* dark_nlw   = (const float*)d_in[9];
    const float* x_m        = (const float*)d_in[10];
    const float* y_m        = (const float*)d_in[11];
    const float* x_b        = (const float*)d_in[12];
    const float* y_b        = (const float*)d_in[13];
    float* out = (float*)d_out;

    dim3 block(256);
    dim3 grid(NT, NT, B_);
    stroke_kernel<<<grid, block, 0, stream>>>(
        param, x_start, y_start, theta, weights, biases,
        thick_mult, thick_bias, dark_exp, dark_nlw,
        x_m, y_m, x_b, y_b, out);
}

// Round 6
// 14.119 us; speedup vs baseline: 1.1041x; 1.1041x over previous
//
#include <hip/hip_runtime.h>
#include <math.h>

#define B_ 64
#define N_ 32
#define H_ 200
#define W_ 200
#define NSEG (N_ - 1)
#define TSX 32                // tile: 32 cols x 16 rows; thread = 1 row x 4 cols
#define TSY 16
#define NTX 7                 // ceil(200/32)
#define NTY 13                // ceil(200/16)
// tile half-diagonal: sqrt(15.5^2 + 7.5^2)/200 = 0.0861 + margin
#define TILE_RAD 0.087f

__global__ __launch_bounds__(128) void stroke_kernel(
    const float* __restrict__ param,      // (B, N, 3)
    const float* __restrict__ x_start,
    const float* __restrict__ y_start,
    const float* __restrict__ theta,
    const float* __restrict__ weights,    // (2,2)
    const float* __restrict__ biases,     // (2,)
    const float* __restrict__ thick_mult,
    const float* __restrict__ thick_bias,
    const float* __restrict__ dark_exp_p,
    const float* __restrict__ dark_nlw_p,
    const float* __restrict__ x_m_p,
    const float* __restrict__ y_m_p,
    const float* __restrict__ x_b_p,
    const float* __restrict__ y_b_p,
    float* __restrict__ out)              // (B, H, W)
{
    // Benign-race LDS: each wave writes identical values and reads only after
    // its own writes (in-wave lgkmcnt order) -> NO __syncthreads needed.
    __shared__ float4 s_A[NSEG];   // (vy, vx, wvy, wvx)
    __shared__ float4 s_B[NSEG];   // (inv_d2, c0, c1, ddot_x = wvx*inv_d2/W)

    const int b    = blockIdx.z;
    const int tid  = threadIdx.x;
    const int lane = tid & 63;

    const float dexp = dark_exp_p[0], dnlw = dark_nlw_p[0];

    // ---- per-wave redundant setup (lanes 0..31 of each of the 2 waves) ----
    float sy = 0.0f, sx = 0.0f, tk = 0.0f;
    const float tm = thick_mult[0], tb = thick_bias[0];
    if (lane < N_) {
        const float thv = theta[0];
        const float c   = __cosf(thv), s = __sinf(thv);   // native v_cos/v_sin
        const float xs  = x_start[0], ys = y_start[0];
        const float W00 = weights[0], W01 = weights[1];
        const float W10 = weights[2], W11 = weights[3];
        const float bb0 = biases[0],  bb1 = biases[1];
        const float xm  = x_m_p[0], ym = y_m_p[0];
        const float xb  = x_b_p[0], yb = y_b_p[0];
        float p0 = param[(b * N_ + lane) * 3 + 0];
        float p1 = param[(b * N_ + lane) * 3 + 1];
        float p2 = param[(b * N_ + lane) * 3 + 2];
        float x0 = p0, y0 = -p1;
        float x_rot =  x0 * c + y0 * s;
        float y_rot = -x0 * s + y0 * c;
        float yy = y_rot * ym + yb + ys;
        float xx = x_rot * xm + xb + xs;
        sy = yy * W00 + xx * W01 + bb0;
        sx = yy * W10 + xx * W11 + bb1;
        tk = (p2 * 2.0f + 0.5f) * (1.0f / 64.0f);
    }
    float sy1 = __shfl_down(sy, 1);
    float sx1 = __shfl_down(sx, 1);
    float tk1 = __shfl_down(tk, 1);

    bool keep = false;
    float4 A4 = make_float4(0,0,0,0), B4 = make_float4(0,0,0,0);
    if (lane < NSEG) {
        float wvy = sy1 - sy, wvx = sx1 - sx;
        float d2 = wvy * wvy + wvx * wvx;
        float inv_d2 = 1.0f / (d2 + 1e-5f);
        float c0 = tk * tm + tb;            // th(frac) = c0 + frac*c1
        float c1 = (tk1 - tk) * tm;
        A4 = make_float4(sy, sx, wvy, wvx);
        B4 = make_float4(inv_d2, c0, c1, wvx * inv_d2 * (1.0f / W_));
        const float cy = ((float)(blockIdx.y * TSY) + 7.5f)  * (1.0f / H_);
        const float cx = ((float)(blockIdx.x * TSX) + 15.5f) * (1.0f / W_);
        float dyc = cy - sy, dxc = cx - sx;
        float dot = (dyc * wvy + dxc * wvx) * inv_d2;
        float fr  = __builtin_amdgcn_fmed3f(dot, 0.0f, 1.0f);
        float ey  = dyc - fr * wvy;
        float ex  = dxc - fr * wvx;
        float e2c = ey * ey + ex * ex;
        float thmax = fmaxf(fmaxf(c0, c0 + c1), 1e-8f);
        float reach = thmax + TILE_RAD;     // beyond -> dark==0 in whole tile
        keep = e2c < reach * reach;
    }
    unsigned long long mask = __ballot(keep);
    const int cnt = (int)__popcll(mask);
    if (keep) {
        int pos = (int)__popcll(mask & ((1ull << lane) - 1ull));
        s_A[pos] = A4; s_B[pos] = B4;
    }
    // order this wave's LDS writes before its reads (no cross-wave dependency)
    asm volatile("s_waitcnt lgkmcnt(0)" ::: "memory");

    // ---- 1 row x 4 adjacent cols per thread ----
    const int ii = tid >> 3;                       // 0..15 row in tile
    const int jj = tid & 7;                        // 0..7  col-group
    const int r  = blockIdx.y * TSY + ii;
    const int c0 = blockIdx.x * TSX + (jj << 2);   // multiple of 4
    const float py  = (float)r  * (1.0f / H_);
    const float px0 = (float)c0 * (1.0f / W_);

    const bool hoist = (dexp > 0.0f) && (dnlw >= 0.0f) && (dnlw <= 1.0f);

    float o0, o1, o2, o3;
    if (hoist) {
        // maximize dark = 1 - sqrt(e2)/th  <=>  minimize q = e2*rcp(th)^2;
        // sqrt once per pixel; final clamp01 subsumes per-seg clamp + culled 0s.
        float q0 = INFINITY, q1 = INFINITY, q2 = INFINITY, q3 = INFINITY;
        if (cnt > 0) {
            float4 A = s_A[0], Bc = s_B[0];
            for (int n = 0; n < cnt; ++n) {
                int np = (n + 1 < cnt) ? n + 1 : n;   // prefetch next
                float4 An = s_A[np], Bn = s_B[np];
                float dy  = py  - A.x;
                float dx0 = px0 - A.y;
                float dx1 = dx0 + 1.0f / W_;
                float dx2 = dx0 + 2.0f / W_;
                float dx3 = dx0 + 3.0f / W_;
                float dot0 = fmaf(dy, A.z, dx0 * A.w) * Bc.x;
                float dot1 = dot0 + Bc.w;
                float dot2 = dot1 + Bc.w;
                float dot3 = dot2 + Bc.w;
                #define PX(dotv, dxv, qm) { \
                    float fr = __builtin_amdgcn_fmed3f(dotv, 0.0f, 1.0f); \
                    float ey = fmaf(-fr, A.z, dy); \
                    float ex = fmaf(-fr, A.w, dxv); \
                    float e2 = fmaf(ey, ey, ex * ex); \
                    float th = fmaxf(fmaf(fr, Bc.z, Bc.y), 1e-8f); \
                    float it = __builtin_amdgcn_rcpf(th); \
                    qm = fminf(qm, (e2 * it) * it); }
                PX(dot0, dx0, q0)
                PX(dot1, dx1, q1)
                PX(dot2, dx2, q2)
                PX(dot3, dx3, q3)
                #undef PX
                A = An; Bc = Bn;
            }
        }
        const bool lin = (dexp == 1.0f);     // uniform: skip pow entirely
        #define EPI(qm, rr) { \
            float md = fminf(fmaxf(1.0f - __builtin_amdgcn_sqrtf(qm), 0.0f), 1.0f); \
            float d  = lin ? (md + 1e-4f) : __expf(dexp * __logf(md + 1e-4f)); \
            float nl = __builtin_amdgcn_rcpf(1.0f + __expf(8.0f - d * 16.0f)); \
            rr = dnlw * nl + (1.0f - dnlw) * d; }
        EPI(q0, o0) EPI(q1, o1) EPI(q2, o2) EPI(q3, o3)
        #undef EPI
    } else {
        // generic fallback: per-segment transform; culled segs contribute T(0)
        float b0 = -INFINITY, b1 = -INFINITY, b2 = -INFINITY, b3 = -INFINITY;
        if (cnt < NSEG) {
            float d0  = __expf(dexp * __logf(1e-4f));
            float nl0 = __builtin_amdgcn_rcpf(1.0f + __expf(8.0f - d0 * 16.0f));
            float t0  = dnlw * nl0 + (1.0f - dnlw) * d0;
            b0 = b1 = b2 = b3 = t0;
        }
        for (int n = 0; n < cnt; ++n) {
            float4 A = s_A[n], Bc = s_B[n];
            float dy  = py  - A.x;
            float dx0 = px0 - A.y;
            float dx1 = dx0 + 1.0f / W_;
            float dx2 = dx0 + 2.0f / W_;
            float dx3 = dx0 + 3.0f / W_;
            float dot0 = fmaf(dy, A.z, dx0 * A.w) * Bc.x;
            float dot1 = dot0 + Bc.w;
            float dot2 = dot1 + Bc.w;
            float dot3 = dot2 + Bc.w;
            #define PXF(dotv, dxv, bb) { \
                float fr = __builtin_amdgcn_fmed3f(dotv, 0.0f, 1.0f); \
                float ey = fmaf(-fr, A.z, dy); \
                float ex = fmaf(-fr, A.w, dxv); \
                float dist = __builtin_amdgcn_sqrtf(fmaf(ey, ey, ex * ex)); \
                float th = fmaxf(fmaf(fr, Bc.z, Bc.y), 1e-8f); \
                float dark = fminf(fmaxf(fmaf(-dist, __builtin_amdgcn_rcpf(th), 1.0f), 0.0f), 1.0f); \
                float d  = __expf(dexp * __logf(dark + 1e-4f)); \
                float nl = __builtin_amdgcn_rcpf(1.0f + __expf(8.0f - d * 16.0f)); \
                bb = fmaxf(bb, dnlw * nl + (1.0f - dnlw) * d); }
            PXF(dot0, dx0, b0)
            PXF(dot1, dx1, b1)
            PXF(dot2, dx2, b2)
            PXF(dot3, dx3, b3)
            #undef PXF
        }
        o0 = b0; o1 = b1; o2 = b2; o3 = b3;
    }

    if (r < H_ && c0 < W_) {   // c0 % 4 == 0, W % 4 == 0 -> quad never straddles
        *reinterpret_cast<float4*>(&out[(b * H_ + r) * W_ + c0]) =
            make_float4(o0, o1, o2, o3);
    }
}

extern "C" void kernel_launch(void* const* d_in, const int* in_sizes, int n_in,
                              void* d_out, int out_size, void* d_ws, size_t ws_size,
                              hipStream_t stream) {
    const float* param      = (const float*)d_in[0];
    const float* x_start    = (const float*)d_in[1];
    const float* y_start    = (const float*)d_in[2];
    const float* theta      = (const float*)d_in[3];
    const float* weights    = (const float*)d_in[4];
    const float* biases     = (const float*)d_in[5];
    const float* thick_mult = (const float*)d_in[6];
    const float* thick_bias = (const float*)d_in[7];
    const float* dark_exp   = (const float*)d_in[8];
    const float* dark_nlw   = (const float*)d_in[9];
    const float* x_m        = (const float*)d_in[10];
    const float* y_m        = (const float*)d_in[11];
    const float* x_b        = (const float*)d_in[12];
    const float* y_b        = (const float*)d_in[13];
    float* out = (float*)d_out;

    dim3 block(128);
    dim3 grid(NTX, NTY, B_);
    stroke_kernel<<<grid, block, 0, stream>>>(
        param, x_start, y_start, theta, weights, biases,
        thick_mult, thick_bias, dark_exp, dark_nlw,
        x_m, y_m, x_b, y_b, out);
}